// Round 11
// baseline (324.598 us; speedup 1.0000x reference)
//
#include <hip/hip_runtime.h>

typedef unsigned short u16;
typedef __attribute__((ext_vector_type(8))) short short8;
typedef __attribute__((ext_vector_type(4))) float f32x4;

#define MFMA(a, b, c) __builtin_amdgcn_mfma_f32_16x16x32_bf16((a), (b), (c), 0, 0, 0)

__device__ inline float bf2f(u16 u) {
  union { unsigned int i; float f; } w; w.i = ((unsigned int)u) << 16; return w.f;
}
__device__ inline u16 f2bf(float x) {
  union { float f; unsigned int i; } u; u.f = x;
  unsigned int r = u.i + 0x7fffu + ((u.i >> 16) & 1u);  // RNE
  return (u16)(r >> 16);
}
__device__ inline unsigned int pk2(float a, float b) {
  return (unsigned int)f2bf(a) | ((unsigned int)f2bf(b) << 16);
}
__device__ inline void unpack8(uint4 v, float* f) {
  union { unsigned int i; float g; } c;
  c.i = v.x << 16;          f[0] = c.g;
  c.i = v.x & 0xffff0000u;  f[1] = c.g;
  c.i = v.y << 16;          f[2] = c.g;
  c.i = v.y & 0xffff0000u;  f[3] = c.g;
  c.i = v.z << 16;          f[4] = c.g;
  c.i = v.z & 0xffff0000u;  f[5] = c.g;
  c.i = v.w << 16;          f[6] = c.g;
  c.i = v.w & 0xffff0000u;  f[7] = c.g;
}

// ---------------- workspace layout (bytes) ----------------
static const size_t SZ_QKV = (size_t)48 * 1024 * 64 * 2;     // 6,291,456
static const size_t SZ_MAP = (size_t)48 * 1024 * 1024 * 2;   // 100,663,296
static const size_t OFF_Q  = 0;
static const size_t OFF_K  = OFF_Q + SZ_QKV;
static const size_t OFF_VT = OFF_K + SZ_QKV;
static const size_t OFF_S  = OFF_VT + SZ_QKV;                // S bf16; DEAD after conv -> U partials alias
static const size_t OFF_U0 = OFF_S;                          // U partial 0, f32 [48][1024][64]
static const size_t OFF_U1 = OFF_S + 12582912;               // U partial 1
static const size_t OFF_QM = OFF_S + SZ_MAP;                 // Q = N*P-1 bf16 [48][1024][1024]
static const size_t OFF_ST = OFF_QM + SZ_MAP;                // stats 48*2 f32
static const size_t OFF_CS = OFF_ST + 896;                   // colsum_v 48*64 f32
static const size_t OFF_AD = OFF_CS + 12288;                 // addend 48*64 f32
static const size_t OFF_AL = OFF_AD + 12288;                 // alpha 48 f32

// ---------------- K1: qkv = x @ w_qkv^T (f32 in, bf16 staged), scatter to q,k,vT ----------------
__global__ __launch_bounds__(256) void k_qkv(const float* __restrict__ x,
                                             const float* __restrict__ w,
                                             u16* __restrict__ qb,
                                             u16* __restrict__ kb,
                                             u16* __restrict__ vT) {
  __shared__ u16 As[128 * 64];
  __shared__ u16 Bs[128 * 64];
  const int t = threadIdx.x;
  const int m0 = blockIdx.x * 128;
  const int n0 = blockIdx.y * 128;
  const int wave = t >> 6, lane = t & 63;
  const int wm = (wave & 1) * 64, wn = (wave >> 1) * 64;
  const int fr = lane & 15;
  const int fk = (lane >> 4) * 8;
  f32x4 acc[4][4] = {};
  for (int k0 = 0; k0 < 384; k0 += 64) {
#pragma unroll
    for (int i = 0; i < 4; ++i) {
      int e = (i * 256 + t) * 8;
      int row = e >> 6, col = e & 63;
      const float* xp = &x[(size_t)(m0 + row) * 384 + k0 + col];
      const float* wp = &w[(size_t)(n0 + row) * 384 + k0 + col];
      float4 a0 = *(const float4*)xp, a1 = *(const float4*)(xp + 4);
      uint4 av; av.x = pk2(a0.x, a0.y); av.y = pk2(a0.z, a0.w);
      av.z = pk2(a1.x, a1.y); av.w = pk2(a1.z, a1.w);
      *(uint4*)&As[e] = av;
      float4 b0 = *(const float4*)wp, b1 = *(const float4*)(wp + 4);
      uint4 bv; bv.x = pk2(b0.x, b0.y); bv.y = pk2(b0.z, b0.w);
      bv.z = pk2(b1.x, b1.y); bv.w = pk2(b1.z, b1.w);
      *(uint4*)&Bs[e] = bv;
    }
    __syncthreads();
#pragma unroll
    for (int ks = 0; ks < 2; ++ks) {
      const int ko = ks * 32 + fk;
      short8 a[4], b[4];
#pragma unroll
      for (int mi = 0; mi < 4; ++mi) a[mi] = *(const short8*)&As[(wm + mi * 16 + fr) * 64 + ko];
#pragma unroll
      for (int ni = 0; ni < 4; ++ni) b[ni] = *(const short8*)&Bs[(wn + ni * 16 + fr) * 64 + ko];
#pragma unroll
      for (int mi = 0; mi < 4; ++mi)
#pragma unroll
        for (int ni = 0; ni < 4; ++ni) acc[mi][ni] = MFMA(a[mi], b[ni], acc[mi][ni]);
    }
    __syncthreads();
  }
#pragma unroll
  for (int mi = 0; mi < 4; ++mi) {
#pragma unroll
    for (int ni = 0; ni < 4; ++ni) {
      int gc = n0 + wn + ni * 16 + fr;            // 0..1151
      int s = gc / 384;
      int rem = gc - s * 384;
      int h = rem >> 6, d = rem & 63;
#pragma unroll
      for (int r = 0; r < 4; ++r) {
        int gm = m0 + wm + mi * 16 + (lane >> 4) * 4 + r;   // 0..8191
        int b_ = gm >> 10, n = gm & 1023;
        u16 val = f2bf(acc[mi][ni][r]);
        size_t base = (size_t)(b_ * 6 + h) << 16;
        if (s == 0)      qb[base + (size_t)n * 64 + d] = val;
        else if (s == 1) kb[base + (size_t)n * 64 + d] = val;
        else             vT[base + (size_t)d * 1024 + n] = val;
      }
    }
  }
}

// ---------------- K2a: S = (q @ k^T) * SCALE, per (b,h) map ----------------
__global__ __launch_bounds__(256) void k_qk(const u16* __restrict__ qb,
                                            const u16* __restrict__ kb,
                                            u16* __restrict__ S) {
  __shared__ u16 As[128 * 64];
  __shared__ u16 Bs[128 * 64];
  const int t = threadIdx.x;
  const int m0 = blockIdx.x * 128, n0 = blockIdx.y * 128;
  const int bh = blockIdx.z;
  const u16* A = qb + ((size_t)bh << 16);
  const u16* Bp = kb + ((size_t)bh << 16);
  const int wave = t >> 6, lane = t & 63;
  const int wm = (wave & 1) * 64, wn = (wave >> 1) * 64;
  const int fr = lane & 15;
  const int fk = (lane >> 4) * 8;
  f32x4 acc[4][4] = {};
#pragma unroll
  for (int i = 0; i < 4; ++i) {
    int e = (i * 256 + t) * 8;
    *(uint4*)&As[e] = *(const uint4*)&A[(size_t)m0 * 64 + e];
    *(uint4*)&Bs[e] = *(const uint4*)&Bp[(size_t)n0 * 64 + e];
  }
  __syncthreads();
#pragma unroll
  for (int ks = 0; ks < 2; ++ks) {
    const int ko = ks * 32 + fk;
    short8 a[4], b[4];
#pragma unroll
    for (int mi = 0; mi < 4; ++mi) a[mi] = *(const short8*)&As[(wm + mi * 16 + fr) * 64 + ko];
#pragma unroll
    for (int ni = 0; ni < 4; ++ni) b[ni] = *(const short8*)&Bs[(wn + ni * 16 + fr) * 64 + ko];
#pragma unroll
    for (int mi = 0; mi < 4; ++mi)
#pragma unroll
      for (int ni = 0; ni < 4; ++ni) acc[mi][ni] = MFMA(a[mi], b[ni], acc[mi][ni]);
  }
  const size_t sb = (size_t)bh << 20;
#pragma unroll
  for (int mi = 0; mi < 4; ++mi)
#pragma unroll
    for (int ni = 0; ni < 4; ++ni) {
      int gc = n0 + wn + ni * 16 + fr;
#pragma unroll
      for (int r = 0; r < 4; ++r) {
        int gm = m0 + wm + mi * 16 + (lane >> 4) * 4 + r;
        S[sb + (size_t)gm * 1024 + gc] = f2bf(acc[mi][ni][r] * 0.125f);
      }
    }
}

// ---------------- K2b: depthwise 3x3 conv + softmax, Q = N*P - 1 (bf16) ----------------
__global__ __launch_bounds__(256) void k_conv_softmax(const u16* __restrict__ S,
                                                      const float* __restrict__ w_kq,
                                                      u16* __restrict__ Qb) {
  __shared__ u16 Sr[10 * 1040];
  __shared__ float red[4];
  const int t = threadIdx.x;
  const int bh = blockIdx.y;
  const int h = bh % 6;
  const int r0 = blockIdx.x * 8;
  const u16* Sp = S + ((size_t)bh << 20);
  float wv[9];
#pragma unroll
  for (int i = 0; i < 9; ++i) wv[i] = w_kq[h * 9 + i];
  if (t < 10) { Sr[t * 1040 + 7] = 0; Sr[t * 1040 + 1032] = 0; }
#pragma unroll
  for (int c = 0; c < 5; ++c) {
    int e = (c * 256 + t) * 8;
    int i = e >> 10, col = e & 1023;
    int g = r0 - 1 + i;
    uint4 val = make_uint4(0u, 0u, 0u, 0u);
    if (g >= 0 && g < 1024) val = *(const uint4*)&Sp[(size_t)g * 1024 + col];
    *(uint4*)&Sr[i * 1040 + 8 + col] = val;
  }
  __syncthreads();
  const int half = t >> 7;
  const int lane = t & 63;
  const int m0 = (t & 127) * 8;
  for (int pass = 0; pass < 4; ++pass) {
    int rr = pass * 2 + half;       // output row in block (0..7)
    float o8[8];
#pragma unroll
    for (int j = 0; j < 8; ++j) o8[j] = 0.f;
#pragma unroll
    for (int i = 0; i < 3; ++i) {
      const u16* rowp = &Sr[(rr + i) * 1040 + 8];
      float left = bf2f(rowp[m0 - 1]);
      float md[8];
      unpack8(*(const uint4*)&rowp[m0], md);
      float right = bf2f(rowp[m0 + 8]);
      float w0 = wv[i * 3 + 0], w1 = wv[i * 3 + 1], w2 = wv[i * 3 + 2];
      o8[0] += w0 * left + w1 * md[0] + w2 * md[1];
#pragma unroll
      for (int j = 1; j < 7; ++j) o8[j] += w0 * md[j - 1] + w1 * md[j] + w2 * md[j + 1];
      o8[7] += w0 * md[6] + w1 * md[7] + w2 * right;
    }
    float mx = o8[0];
#pragma unroll
    for (int j = 1; j < 8; ++j) mx = fmaxf(mx, o8[j]);
    for (int off = 32; off; off >>= 1) mx = fmaxf(mx, __shfl_xor(mx, off, 64));
    if (lane == 0) red[t >> 6] = mx;
    __syncthreads();
    float rmax = fmaxf(red[half * 2], red[half * 2 + 1]);
    __syncthreads();
    float e8[8], s = 0.f;
#pragma unroll
    for (int j = 0; j < 8; ++j) { e8[j] = __expf(o8[j] - rmax); s += e8[j]; }
    for (int off = 32; off; off >>= 1) s += __shfl_xor(s, off, 64);
    if (lane == 0) red[t >> 6] = s;
    __syncthreads();
    float rsum = red[half * 2] + red[half * 2 + 1];
    __syncthreads();
    float scale = 1024.f / rsum;
    unsigned int pk[4];
#pragma unroll
    for (int jj = 0; jj < 4; ++jj)
      pk[jj] = pk2(e8[2 * jj] * scale - 1.f, e8[2 * jj + 1] * scale - 1.f);
    int n = r0 + rr;
    *(uint4*)&Qb[((size_t)bh << 20) + (size_t)n * 1024 + m0] = make_uint4(pk[0], pk[1], pk[2], pk[3]);
  }
}

// ---------------- K3b: colsum_v[bh][d] = sum_n vT[bh][d][n] ----------------
__global__ __launch_bounds__(256) void k_colsum(const u16* __restrict__ vT,
                                                float* __restrict__ colsum) {
  __shared__ float acc[64];
  const int t = threadIdx.x;
  const int bh = blockIdx.x;
  if (t < 64) acc[t] = 0.f;
  __syncthreads();
  const int lane = t & 63;
  for (int c = 0; c < 32; ++c) {
    size_t l = (size_t)c * 2048 + (size_t)t * 8;
    uint4 u = *(const uint4*)&vT[((size_t)bh << 16) + l];
    float f[8];
    unpack8(u, f);
    float part = f[0] + f[1] + f[2] + f[3] + f[4] + f[5] + f[6] + f[7];
    for (int off = 32; off; off >>= 1) part += __shfl_xor(part, off, 64);
    if (lane == 0) atomicAdd(&acc[(int)(l >> 10)], part);
  }
  __syncthreads();
  if (t < 64) colsum[bh * 64 + t] = acc[t];
}

// ---------------- K5: PV, 2 output heads per block, m-split 2, mix-on-the-fly + stats ----------------
// grid (32, 8, 3): x = n-tile(16)*2 + m-half, y = batch, z = o-pair.
// Q hexad unpacked ONCE feeds two A~ tiles -> 16 MFMA/wave per barrier pair.
__global__ __launch_bounds__(256) void k_pvmix(const u16* __restrict__ Qm,
                                               const u16* __restrict__ vT,
                                               const float* __restrict__ wh,
                                               float* __restrict__ U0,
                                               float* __restrict__ U1,
                                               float* __restrict__ stats) {
  __shared__ u16 Am[2][64 * 72];
  __shared__ u16 Vm[2][64 * 72];
  const int t = threadIdx.x;
  const int n0 = (blockIdx.x >> 1) * 64;
  const int mh = blockIdx.x & 1;
  const int b_ = blockIdx.y;
  const int o0 = blockIdx.z * 2;
  const int bo0 = b_ * 6 + o0;
  const int wave = t >> 6, lane = t & 63;
  const int fr = lane & 15, quad = lane >> 4;
  const int ow = wave >> 1;       // which o this wave computes
  const int dh = wave & 1;        // d half (32 cols)
  const int srow = t >> 3, smg8 = (t & 7) * 8;
  float wo[2][6];
#pragma unroll
  for (int oi = 0; oi < 2; ++oi)
#pragma unroll
    for (int hh = 0; hh < 6; ++hh) wo[oi][hh] = wh[(o0 + oi) * 6 + hh];
  const size_t qbase = ((size_t)(b_ * 6)) << 20;
  const u16* vp0 = vT + ((size_t)bo0 << 16);
  const u16* vp1 = vT + ((size_t)(bo0 + 1) << 16);
  const int mstart = mh * 512;
  uint4 qpre[2][6];
  uint4 vpre[2][2];
  {
    const int m = mstart + smg8;
#pragma unroll
    for (int i = 0; i < 2; ++i)
#pragma unroll
      for (int hh = 0; hh < 6; ++hh)
        qpre[i][hh] = *(const uint4*)&Qm[qbase + (((size_t)hh) << 20) +
                                         (size_t)(n0 + i * 32 + srow) * 1024 + m];
    vpre[0][0] = *(const uint4*)&vp0[(size_t)srow * 1024 + m];
    vpre[0][1] = *(const uint4*)&vp0[(size_t)(32 + srow) * 1024 + m];
    vpre[1][0] = *(const uint4*)&vp1[(size_t)srow * 1024 + m];
    vpre[1][1] = *(const uint4*)&vp1[(size_t)(32 + srow) * 1024 + m];
  }
  f32x4 acc[4][2] = {};
  float s1[2] = {0.f, 0.f}, s2[2] = {0.f, 0.f};
  for (int mc = 0; mc < 8; ++mc) {
    __syncthreads();   // prev MFMA done reading Am/Vm
    // consume prefetched regs: unpack hexad once, mix both o's, stats, stage
#pragma unroll
    for (int i = 0; i < 2; ++i) {
      float qf[6][8];
#pragma unroll
      for (int hh = 0; hh < 6; ++hh) unpack8(qpre[i][hh], qf[hh]);
#pragma unroll
      for (int oi = 0; oi < 2; ++oi) {
        float mix[8] = {0.f, 0.f, 0.f, 0.f, 0.f, 0.f, 0.f, 0.f};
#pragma unroll
        for (int hh = 0; hh < 6; ++hh) {
          float w = wo[oi][hh];
#pragma unroll
          for (int j = 0; j < 8; ++j) mix[j] += w * qf[hh][j];
        }
#pragma unroll
        for (int j = 0; j < 8; ++j) { s1[oi] += mix[j]; s2[oi] += mix[j] * mix[j]; }
        uint4 pk4;
        pk4.x = pk2(mix[0], mix[1]); pk4.y = pk2(mix[2], mix[3]);
        pk4.z = pk2(mix[4], mix[5]); pk4.w = pk2(mix[6], mix[7]);
        *(uint4*)&Am[oi][(i * 32 + srow) * 72 + smg8] = pk4;
      }
    }
    *(uint4*)&Vm[0][srow * 72 + smg8] = vpre[0][0];
    *(uint4*)&Vm[0][(32 + srow) * 72 + smg8] = vpre[0][1];
    *(uint4*)&Vm[1][srow * 72 + smg8] = vpre[1][0];
    *(uint4*)&Vm[1][(32 + srow) * 72 + smg8] = vpre[1][1];
    // prefetch next chunk (overlaps barrier + MFMA)
    if (mc < 7) {
      const int m = mstart + (mc + 1) * 64 + smg8;
#pragma unroll
      for (int i = 0; i < 2; ++i)
#pragma unroll
        for (int hh = 0; hh < 6; ++hh)
          qpre[i][hh] = *(const uint4*)&Qm[qbase + (((size_t)hh) << 20) +
                                           (size_t)(n0 + i * 32 + srow) * 1024 + m];
      vpre[0][0] = *(const uint4*)&vp0[(size_t)srow * 1024 + m];
      vpre[0][1] = *(const uint4*)&vp0[(size_t)(32 + srow) * 1024 + m];
      vpre[1][0] = *(const uint4*)&vp1[(size_t)srow * 1024 + m];
      vpre[1][1] = *(const uint4*)&vp1[(size_t)(32 + srow) * 1024 + m];
    }
    __syncthreads();   // staging visible
#pragma unroll
    for (int ks = 0; ks < 2; ++ks) {
      short8 a[4];
#pragma unroll
      for (int nt = 0; nt < 4; ++nt)
        a[nt] = *(const short8*)&Am[ow][(nt * 16 + fr) * 72 + ks * 32 + quad * 8];
#pragma unroll
      for (int ni = 0; ni < 2; ++ni) {
        short8 b = *(const short8*)&Vm[ow][(dh * 32 + ni * 16 + fr) * 72 + ks * 32 + quad * 8];
#pragma unroll
        for (int nt = 0; nt < 4; ++nt) acc[nt][ni] = MFMA(a[nt], b, acc[nt][ni]);
      }
    }
  }
  float* Up = mh ? U1 : U0;
  const int bo = bo0 + ow;
#pragma unroll
  for (int nt = 0; nt < 4; ++nt)
#pragma unroll
    for (int ni = 0; ni < 2; ++ni) {
      int d = dh * 32 + ni * 16 + fr;
#pragma unroll
      for (int r = 0; r < 4; ++r) {
        int n = n0 + nt * 16 + quad * 4 + r;
        Up[((size_t)(bo * 1024 + n)) * 64 + d] = acc[nt][ni][r];
      }
    }
#pragma unroll
  for (int oi = 0; oi < 2; ++oi) {
    float a = s1[oi], q = s2[oi];
    for (int off = 32; off; off >>= 1) {
      a += __shfl_xor(a, off, 64);
      q += __shfl_xor(q, off, 64);
    }
    if (lane == 0) {
      atomicAdd(&stats[(bo0 + oi) * 2 + 0], a);
      atomicAdd(&stats[(bo0 + oi) * 2 + 1], q);
    }
  }
}

// ---------------- K4: finalize GN constants ----------------
__global__ __launch_bounds__(256) void k_finalize(const float* __restrict__ stats,
                                                  const float* __restrict__ colsum,
                                                  const float* __restrict__ gn_w,
                                                  const float* __restrict__ gn_b,
                                                  float* __restrict__ addend,
                                                  float* __restrict__ alphaArr) {
  int gid = blockIdx.x * 256 + threadIdx.x;   // 0..3071
  int bo = gid >> 6, d = gid & 63;
  int o = bo % 6;
  float s1 = stats[bo * 2], s2 = stats[bo * 2 + 1];
  const float inv = 1.f / 1048576.f;
  float mu = s1 * inv;
  float var = s2 * inv - mu * mu;
  float alpha = gn_w[o] * rsqrtf(var + 1e-5f * 1048576.f);
  float beta = gn_b[o] - alpha * mu;
  addend[gid] = beta * colsum[gid];
  if (d == 0) alphaArr[bo] = alpha;
}

// ---------------- K6: out(F32) = GN-apply(U0+U1) @ w_proj^T + b_proj (apply fused in staging) ----------------
__global__ __launch_bounds__(256) void k_proj(const float* __restrict__ U0,
                                              const float* __restrict__ U1,
                                              const float* __restrict__ alphaArr,
                                              const float* __restrict__ addend,
                                              const float* __restrict__ w,
                                              const float* __restrict__ bias,
                                              float* __restrict__ out) {
  __shared__ u16 As[128 * 64];
  __shared__ u16 Bs[128 * 64];
  const int t = threadIdx.x;
  const int m0 = blockIdx.x * 128;
  const int n0 = blockIdx.y * 128;
  const int wave = t >> 6, lane = t & 63;
  const int wm = (wave & 1) * 64, wn = (wave >> 1) * 64;
  const int fr = lane & 15;
  const int fk = (lane >> 4) * 8;
  f32x4 acc[4][4] = {};
  for (int k0 = 0; k0 < 384; k0 += 64) {
#pragma unroll
    for (int i = 0; i < 4; ++i) {
      int e = (i * 256 + t) * 8;
      int row = e >> 6, col = e & 63;
      // A-staging with fused GN apply: a = alpha*(U0+U1) + addend  (bit-identical to old k_apply)
      int gm = m0 + row;
      int b_ = gm >> 10, n = gm & 1023;
      int c = k0 + col;
      int o = c >> 6, d0 = c & 63;
      int bo = b_ * 6 + o;
      size_t ue = ((size_t)(bo * 1024 + n)) * 64 + d0;
      float4 u0a = *(const float4*)&U0[ue], u0b = *(const float4*)&U0[ue + 4];
      float4 u1a = *(const float4*)&U1[ue], u1b = *(const float4*)&U1[ue + 4];
      float al = alphaArr[bo];
      const float* ap = &addend[bo * 64 + d0];
      uint4 av;
      av.x = pk2(al * (u0a.x + u1a.x) + ap[0], al * (u0a.y + u1a.y) + ap[1]);
      av.y = pk2(al * (u0a.z + u1a.z) + ap[2], al * (u0a.w + u1a.w) + ap[3]);
      av.z = pk2(al * (u0b.x + u1b.x) + ap[4], al * (u0b.y + u1b.y) + ap[5]);
      av.w = pk2(al * (u0b.z + u1b.z) + ap[6], al * (u0b.w + u1b.w) + ap[7]);
      *(uint4*)&As[e] = av;
      const float* wp = &w[(size_t)(n0 + row) * 384 + k0 + col];
      float4 b0 = *(const float4*)wp, b1 = *(const float4*)(wp + 4);
      uint4 bv; bv.x = pk2(b0.x, b0.y); bv.y = pk2(b0.z, b0.w);
      bv.z = pk2(b1.x, b1.y); bv.w = pk2(b1.z, b1.w);
      *(uint4*)&Bs[e] = bv;
    }
    __syncthreads();
#pragma unroll
    for (int ks = 0; ks < 2; ++ks) {
      const int ko = ks * 32 + fk;
      short8 a[4], b[4];
#pragma unroll
      for (int mi = 0; mi < 4; ++mi) a[mi] = *(const short8*)&As[(wm + mi * 16 + fr) * 64 + ko];
#pragma unroll
      for (int ni = 0; ni < 4; ++ni) b[ni] = *(const short8*)&Bs[(wn + ni * 16 + fr) * 64 + ko];
#pragma unroll
      for (int mi = 0; mi < 4; ++mi)
#pragma unroll
        for (int ni = 0; ni < 4; ++ni) acc[mi][ni] = MFMA(a[mi], b[ni], acc[mi][ni]);
    }
    __syncthreads();
  }
#pragma unroll
  for (int mi = 0; mi < 4; ++mi)
#pragma unroll
    for (int ni = 0; ni < 4; ++ni) {
      int gc = n0 + wn + ni * 16 + fr;
      float bv = bias[gc];
#pragma unroll
      for (int r = 0; r < 4; ++r) {
        int gm = m0 + wm + mi * 16 + (lane >> 4) * 4 + r;
        out[(size_t)gm * 384 + gc] = acc[mi][ni][r] + bv;   // FLOAT32 output
      }
    }
}

extern "C" void kernel_launch(void* const* d_in, const int* in_sizes, int n_in,
                              void* d_out, int out_size, void* d_ws, size_t ws_size,
                              hipStream_t stream) {
  (void)in_sizes; (void)n_in; (void)out_size; (void)ws_size;
  const float* x      = (const float*)d_in[0];
  const float* w_qkv  = (const float*)d_in[1];
  const float* w_proj = (const float*)d_in[2];
  const float* b_proj = (const float*)d_in[3];
  const float* w_kq   = (const float*)d_in[4];
  // d_in[5] b_kq: constant per map -> softmax-invariant, unused
  const float* w_head = (const float*)d_in[6];
  // d_in[7] b_head: constant per (b,o) map -> cancelled by GroupNorm, unused
  const float* gn_w   = (const float*)d_in[8];
  const float* gn_b   = (const float*)d_in[9];

  char* ws = (char*)d_ws;
  u16*   qb      = (u16*)(ws + OFF_Q);
  u16*   kb      = (u16*)(ws + OFF_K);
  u16*   vT      = (u16*)(ws + OFF_VT);
  u16*   Sb      = (u16*)(ws + OFF_S);
  float* U0      = (float*)(ws + OFF_U0);   // aliases S (dead after conv)
  float* U1      = (float*)(ws + OFF_U1);
  u16*   Qm      = (u16*)(ws + OFF_QM);
  float* stats   = (float*)(ws + OFF_ST);
  float* colsum  = (float*)(ws + OFF_CS);
  float* addend  = (float*)(ws + OFF_AD);
  float* alphaA  = (float*)(ws + OFF_AL);

  hipMemsetAsync(stats, 0, 512, stream);
  k_qkv<<<dim3(64, 9), 256, 0, stream>>>(x, w_qkv, qb, kb, vT);
  k_qk<<<dim3(8, 8, 48), 256, 0, stream>>>(qb, kb, Sb);
  k_conv_softmax<<<dim3(128, 48), 256, 0, stream>>>(Sb, w_kq, Qm);
  k_colsum<<<dim3(48), 256, 0, stream>>>(vT, colsum);
  k_pvmix<<<dim3(32, 8, 3), 256, 0, stream>>>(Qm, vT, w_head, U0, U1, stats);
  k_finalize<<<dim3(12), 256, 0, stream>>>(stats, colsum, gn_w, gn_b, addend, alphaA);
  k_proj<<<dim3(64, 3), 256, 0, stream>>>(U0, U1, alphaA, addend, w_proj, b_proj, (float*)d_out);
}

// Round 12
// 308.163 us; speedup vs baseline: 1.0533x; 1.0533x over previous
//
#include <hip/hip_runtime.h>

typedef unsigned short u16;
typedef __attribute__((ext_vector_type(8))) short short8;
typedef __attribute__((ext_vector_type(4))) float f32x4;

#define MFMA(a, b, c) __builtin_amdgcn_mfma_f32_16x16x32_bf16((a), (b), (c), 0, 0, 0)

__device__ inline float bf2f(u16 u) {
  union { unsigned int i; float f; } w; w.i = ((unsigned int)u) << 16; return w.f;
}
__device__ inline u16 f2bf(float x) {
  union { float f; unsigned int i; } u; u.f = x;
  unsigned int r = u.i + 0x7fffu + ((u.i >> 16) & 1u);  // RNE
  return (u16)(r >> 16);
}
__device__ inline unsigned int pk2(float a, float b) {
  return (unsigned int)f2bf(a) | ((unsigned int)f2bf(b) << 16);
}
__device__ inline void unpack8(uint4 v, float* f) {
  union { unsigned int i; float g; } c;
  c.i = v.x << 16;          f[0] = c.g;
  c.i = v.x & 0xffff0000u;  f[1] = c.g;
  c.i = v.y << 16;          f[2] = c.g;
  c.i = v.y & 0xffff0000u;  f[3] = c.g;
  c.i = v.z << 16;          f[4] = c.g;
  c.i = v.z & 0xffff0000u;  f[5] = c.g;
  c.i = v.w << 16;          f[6] = c.g;
  c.i = v.w & 0xffff0000u;  f[7] = c.g;
}

// ---------------- workspace layout (bytes) ----------------
static const size_t SZ_QKV = (size_t)48 * 1024 * 64 * 2;     // 6,291,456
static const size_t SZ_MAP = (size_t)48 * 1024 * 1024 * 2;   // 100,663,296
static const size_t OFF_Q  = 0;
static const size_t OFF_K  = OFF_Q + SZ_QKV;
static const size_t OFF_VT = OFF_K + SZ_QKV;
static const size_t OFF_S  = OFF_VT + SZ_QKV;                // S bf16; DEAD after conv -> U aliases
static const size_t OFF_UG = OFF_S;                          // U f32 [48][1024][64] (aliases S)
static const size_t OFF_QM = OFF_S + SZ_MAP;                 // Q = N*P-1 bf16 [48][1024][1024]
static const size_t OFF_OT = OFF_QM + SZ_MAP;                // o_tmp [B,N,C] bf16
static const size_t OFF_ST = OFF_OT + SZ_QKV;                // stats 48*2 f32
static const size_t OFF_CS = OFF_ST + 896;                   // colsum_v 48*64 f32
static const size_t OFF_AD = OFF_CS + 12288;                 // addend 48*64 f32
static const size_t OFF_AL = OFF_AD + 12288;                 // alpha 48 f32

// ---------------- K1: qkv = x @ w_qkv^T (f32 in, bf16 staged), scatter to q,k,vT ----------------
__global__ __launch_bounds__(256) void k_qkv(const float* __restrict__ x,
                                             const float* __restrict__ w,
                                             u16* __restrict__ qb,
                                             u16* __restrict__ kb,
                                             u16* __restrict__ vT) {
  __shared__ u16 As[128 * 64];
  __shared__ u16 Bs[128 * 64];
  const int t = threadIdx.x;
  const int m0 = blockIdx.x * 128;
  const int n0 = blockIdx.y * 128;
  const int wave = t >> 6, lane = t & 63;
  const int wm = (wave & 1) * 64, wn = (wave >> 1) * 64;
  const int fr = lane & 15;
  const int fk = (lane >> 4) * 8;
  f32x4 acc[4][4] = {};
  for (int k0 = 0; k0 < 384; k0 += 64) {
#pragma unroll
    for (int i = 0; i < 4; ++i) {
      int e = (i * 256 + t) * 8;
      int row = e >> 6, col = e & 63;
      const float* xp = &x[(size_t)(m0 + row) * 384 + k0 + col];
      const float* wp = &w[(size_t)(n0 + row) * 384 + k0 + col];
      float4 a0 = *(const float4*)xp, a1 = *(const float4*)(xp + 4);
      uint4 av; av.x = pk2(a0.x, a0.y); av.y = pk2(a0.z, a0.w);
      av.z = pk2(a1.x, a1.y); av.w = pk2(a1.z, a1.w);
      *(uint4*)&As[e] = av;
      float4 b0 = *(const float4*)wp, b1 = *(const float4*)(wp + 4);
      uint4 bv; bv.x = pk2(b0.x, b0.y); bv.y = pk2(b0.z, b0.w);
      bv.z = pk2(b1.x, b1.y); bv.w = pk2(b1.z, b1.w);
      *(uint4*)&Bs[e] = bv;
    }
    __syncthreads();
#pragma unroll
    for (int ks = 0; ks < 2; ++ks) {
      const int ko = ks * 32 + fk;
      short8 a[4], b[4];
#pragma unroll
      for (int mi = 0; mi < 4; ++mi) a[mi] = *(const short8*)&As[(wm + mi * 16 + fr) * 64 + ko];
#pragma unroll
      for (int ni = 0; ni < 4; ++ni) b[ni] = *(const short8*)&Bs[(wn + ni * 16 + fr) * 64 + ko];
#pragma unroll
      for (int mi = 0; mi < 4; ++mi)
#pragma unroll
        for (int ni = 0; ni < 4; ++ni) acc[mi][ni] = MFMA(a[mi], b[ni], acc[mi][ni]);
    }
    __syncthreads();
  }
#pragma unroll
  for (int mi = 0; mi < 4; ++mi) {
#pragma unroll
    for (int ni = 0; ni < 4; ++ni) {
      int gc = n0 + wn + ni * 16 + fr;            // 0..1151
      int s = gc / 384;
      int rem = gc - s * 384;
      int h = rem >> 6, d = rem & 63;
#pragma unroll
      for (int r = 0; r < 4; ++r) {
        int gm = m0 + wm + mi * 16 + (lane >> 4) * 4 + r;   // 0..8191
        int b_ = gm >> 10, n = gm & 1023;
        u16 val = f2bf(acc[mi][ni][r]);
        size_t base = (size_t)(b_ * 6 + h) << 16;
        if (s == 0)      qb[base + (size_t)n * 64 + d] = val;
        else if (s == 1) kb[base + (size_t)n * 64 + d] = val;
        else             vT[base + (size_t)d * 1024 + n] = val;
      }
    }
  }
}

// ---------------- K2a: S = (q @ k^T) * SCALE, per (b,h) map ----------------
__global__ __launch_bounds__(256) void k_qk(const u16* __restrict__ qb,
                                            const u16* __restrict__ kb,
                                            u16* __restrict__ S) {
  __shared__ u16 As[128 * 64];
  __shared__ u16 Bs[128 * 64];
  const int t = threadIdx.x;
  const int m0 = blockIdx.x * 128, n0 = blockIdx.y * 128;
  const int bh = blockIdx.z;
  const u16* A = qb + ((size_t)bh << 16);
  const u16* Bp = kb + ((size_t)bh << 16);
  const int wave = t >> 6, lane = t & 63;
  const int wm = (wave & 1) * 64, wn = (wave >> 1) * 64;
  const int fr = lane & 15;
  const int fk = (lane >> 4) * 8;
  f32x4 acc[4][4] = {};
#pragma unroll
  for (int i = 0; i < 4; ++i) {
    int e = (i * 256 + t) * 8;
    *(uint4*)&As[e] = *(const uint4*)&A[(size_t)m0 * 64 + e];
    *(uint4*)&Bs[e] = *(const uint4*)&Bp[(size_t)n0 * 64 + e];
  }
  __syncthreads();
#pragma unroll
  for (int ks = 0; ks < 2; ++ks) {
    const int ko = ks * 32 + fk;
    short8 a[4], b[4];
#pragma unroll
    for (int mi = 0; mi < 4; ++mi) a[mi] = *(const short8*)&As[(wm + mi * 16 + fr) * 64 + ko];
#pragma unroll
    for (int ni = 0; ni < 4; ++ni) b[ni] = *(const short8*)&Bs[(wn + ni * 16 + fr) * 64 + ko];
#pragma unroll
    for (int mi = 0; mi < 4; ++mi)
#pragma unroll
      for (int ni = 0; ni < 4; ++ni) acc[mi][ni] = MFMA(a[mi], b[ni], acc[mi][ni]);
  }
  const size_t sb = (size_t)bh << 20;
#pragma unroll
  for (int mi = 0; mi < 4; ++mi)
#pragma unroll
    for (int ni = 0; ni < 4; ++ni) {
      int gc = n0 + wn + ni * 16 + fr;
#pragma unroll
      for (int r = 0; r < 4; ++r) {
        int gm = m0 + wm + mi * 16 + (lane >> 4) * 4 + r;
        S[sb + (size_t)gm * 1024 + gc] = f2bf(acc[mi][ni][r] * 0.125f);
      }
    }
}

// ---------------- K2b: depthwise 3x3 conv + softmax, Q = N*P - 1 (bf16) ----------------
__global__ __launch_bounds__(256) void k_conv_softmax(const u16* __restrict__ S,
                                                      const float* __restrict__ w_kq,
                                                      u16* __restrict__ Qb) {
  __shared__ u16 Sr[10 * 1040];
  __shared__ float red[4];
  const int t = threadIdx.x;
  const int bh = blockIdx.y;
  const int h = bh % 6;
  const int r0 = blockIdx.x * 8;
  const u16* Sp = S + ((size_t)bh << 20);
  float wv[9];
#pragma unroll
  for (int i = 0; i < 9; ++i) wv[i] = w_kq[h * 9 + i];
  if (t < 10) { Sr[t * 1040 + 7] = 0; Sr[t * 1040 + 1032] = 0; }
#pragma unroll
  for (int c = 0; c < 5; ++c) {
    int e = (c * 256 + t) * 8;
    int i = e >> 10, col = e & 1023;
    int g = r0 - 1 + i;
    uint4 val = make_uint4(0u, 0u, 0u, 0u);
    if (g >= 0 && g < 1024) val = *(const uint4*)&Sp[(size_t)g * 1024 + col];
    *(uint4*)&Sr[i * 1040 + 8 + col] = val;
  }
  __syncthreads();
  const int half = t >> 7;
  const int lane = t & 63;
  const int m0 = (t & 127) * 8;
  for (int pass = 0; pass < 4; ++pass) {
    int rr = pass * 2 + half;       // output row in block (0..7)
    float o8[8];
#pragma unroll
    for (int j = 0; j < 8; ++j) o8[j] = 0.f;
#pragma unroll
    for (int i = 0; i < 3; ++i) {
      const u16* rowp = &Sr[(rr + i) * 1040 + 8];
      float left = bf2f(rowp[m0 - 1]);
      float md[8];
      unpack8(*(const uint4*)&rowp[m0], md);
      float right = bf2f(rowp[m0 + 8]);
      float w0 = wv[i * 3 + 0], w1 = wv[i * 3 + 1], w2 = wv[i * 3 + 2];
      o8[0] += w0 * left + w1 * md[0] + w2 * md[1];
#pragma unroll
      for (int j = 1; j < 7; ++j) o8[j] += w0 * md[j - 1] + w1 * md[j] + w2 * md[j + 1];
      o8[7] += w0 * md[6] + w1 * md[7] + w2 * right;
    }
    float mx = o8[0];
#pragma unroll
    for (int j = 1; j < 8; ++j) mx = fmaxf(mx, o8[j]);
    for (int off = 32; off; off >>= 1) mx = fmaxf(mx, __shfl_xor(mx, off, 64));
    if (lane == 0) red[t >> 6] = mx;
    __syncthreads();
    float rmax = fmaxf(red[half * 2], red[half * 2 + 1]);
    __syncthreads();
    float e8[8], s = 0.f;
#pragma unroll
    for (int j = 0; j < 8; ++j) { e8[j] = __expf(o8[j] - rmax); s += e8[j]; }
    for (int off = 32; off; off >>= 1) s += __shfl_xor(s, off, 64);
    if (lane == 0) red[t >> 6] = s;
    __syncthreads();
    float rsum = red[half * 2] + red[half * 2 + 1];
    __syncthreads();
    float scale = 1024.f / rsum;
    unsigned int pk[4];
#pragma unroll
    for (int jj = 0; jj < 4; ++jj)
      pk[jj] = pk2(e8[2 * jj] * scale - 1.f, e8[2 * jj + 1] * scale - 1.f);
    int n = r0 + rr;
    *(uint4*)&Qb[((size_t)bh << 20) + (size_t)n * 1024 + m0] = make_uint4(pk[0], pk[1], pk[2], pk[3]);
  }
}

// ---------------- K3b: colsum_v[bh][d] = sum_n vT[bh][d][n] ----------------
__global__ __launch_bounds__(256) void k_colsum(const u16* __restrict__ vT,
                                                float* __restrict__ colsum) {
  __shared__ float acc[64];
  const int t = threadIdx.x;
  const int bh = blockIdx.x;
  if (t < 64) acc[t] = 0.f;
  __syncthreads();
  const int lane = t & 63;
  for (int c = 0; c < 32; ++c) {
    size_t l = (size_t)c * 2048 + (size_t)t * 8;
    uint4 u = *(const uint4*)&vT[((size_t)bh << 16) + l];
    float f[8];
    unpack8(u, f);
    float part = f[0] + f[1] + f[2] + f[3] + f[4] + f[5] + f[6] + f[7];
    for (int off = 32; off; off >>= 1) part += __shfl_xor(part, off, 64);
    if (lane == 0) atomicAdd(&acc[(int)(l >> 10)], part);
  }
  __syncthreads();
  if (t < 64) colsum[bh * 64 + t] = acc[t];
}

// ---------------- K5: PV (r8 geometry) + mix-on-the-fly + fused stats + reg prefetch ----------------
// grid (16, 48): 64-row n tiles, full m loop (16 chunks, 8 MFMA/wave/chunk). Single U (f32).
__global__ __launch_bounds__(256) void k_pvmix(const u16* __restrict__ Qm,
                                               const u16* __restrict__ vT,
                                               const float* __restrict__ wh,
                                               float* __restrict__ Ug,
                                               float* __restrict__ stats) {
  __shared__ u16 Am[64 * 72];
  __shared__ u16 Vm[64 * 72];
  const int t = threadIdx.x;
  const int n0 = blockIdx.x * 64;
  const int bo = blockIdx.y;
  const int b_ = bo / 6, o = bo - b_ * 6;
  const int wave = t >> 6, lane = t & 63;
  const int fr = lane & 15, quad = lane >> 4;
  const int srow = t >> 3, smg8 = (t & 7) * 8;   // staging: rows srow, srow+32
  float wo[6];
#pragma unroll
  for (int hh = 0; hh < 6; ++hh) wo[hh] = wh[o * 6 + hh];
  const size_t qbase = ((size_t)(b_ * 6)) << 20;
  const u16* vp = vT + ((size_t)bo << 16);
  uint4 qpre[2][6];
  uint4 vpre[2];
  {
    const int m = smg8;
#pragma unroll
    for (int i = 0; i < 2; ++i)
#pragma unroll
      for (int hh = 0; hh < 6; ++hh)
        qpre[i][hh] = *(const uint4*)&Qm[qbase + (((size_t)hh) << 20) +
                                         (size_t)(n0 + i * 32 + srow) * 1024 + m];
    vpre[0] = *(const uint4*)&vp[(size_t)srow * 1024 + m];
    vpre[1] = *(const uint4*)&vp[(size_t)(32 + srow) * 1024 + m];
  }
  f32x4 acc[4] = {};
  float s1 = 0.f, s2 = 0.f;
  for (int mc = 0; mc < 16; ++mc) {
    __syncthreads();   // prev MFMA done reading Am/Vm
    // consume prefetched regs: mix + stats + stage
#pragma unroll
    for (int i = 0; i < 2; ++i) {
      float mix[8] = {0.f, 0.f, 0.f, 0.f, 0.f, 0.f, 0.f, 0.f};
#pragma unroll
      for (int hh = 0; hh < 6; ++hh) {
        float qf[8];
        unpack8(qpre[i][hh], qf);
        float w = wo[hh];
#pragma unroll
        for (int j = 0; j < 8; ++j) mix[j] += w * qf[j];
      }
#pragma unroll
      for (int j = 0; j < 8; ++j) { s1 += mix[j]; s2 += mix[j] * mix[j]; }
      uint4 pk4;
      pk4.x = pk2(mix[0], mix[1]); pk4.y = pk2(mix[2], mix[3]);
      pk4.z = pk2(mix[4], mix[5]); pk4.w = pk2(mix[6], mix[7]);
      *(uint4*)&Am[(i * 32 + srow) * 72 + smg8] = pk4;
    }
    *(uint4*)&Vm[srow * 72 + smg8] = vpre[0];
    *(uint4*)&Vm[(32 + srow) * 72 + smg8] = vpre[1];
    // prefetch next chunk (overlaps barrier + MFMA)
    if (mc < 15) {
      const int m = (mc + 1) * 64 + smg8;
#pragma unroll
      for (int i = 0; i < 2; ++i)
#pragma unroll
        for (int hh = 0; hh < 6; ++hh)
          qpre[i][hh] = *(const uint4*)&Qm[qbase + (((size_t)hh) << 20) +
                                           (size_t)(n0 + i * 32 + srow) * 1024 + m];
      vpre[0] = *(const uint4*)&vp[(size_t)srow * 1024 + m];
      vpre[1] = *(const uint4*)&vp[(size_t)(32 + srow) * 1024 + m];
    }
    __syncthreads();   // staging visible
#pragma unroll
    for (int ks = 0; ks < 2; ++ks) {
      short8 a = *(const short8*)&Am[(wave * 16 + fr) * 72 + ks * 32 + quad * 8];
#pragma unroll
      for (int ni = 0; ni < 4; ++ni) {
        short8 b = *(const short8*)&Vm[(ni * 16 + fr) * 72 + ks * 32 + quad * 8];
        acc[ni] = MFMA(a, b, acc[ni]);
      }
    }
  }
  // write U (f32, unnormalized, full-K accumulation)
#pragma unroll
  for (int ni = 0; ni < 4; ++ni) {
    int d = ni * 16 + fr;
#pragma unroll
    for (int r = 0; r < 4; ++r) {
      int n = n0 + wave * 16 + quad * 4 + r;
      Ug[((size_t)(bo * 1024 + n)) * 64 + d] = acc[ni][r];
    }
  }
  for (int off = 32; off; off >>= 1) {
    s1 += __shfl_xor(s1, off, 64);
    s2 += __shfl_xor(s2, off, 64);
  }
  if (lane == 0) {
    atomicAdd(&stats[bo * 2 + 0], s1);
    atomicAdd(&stats[bo * 2 + 1], s2);
  }
}

// ---------------- K4: finalize GN constants ----------------
__global__ __launch_bounds__(256) void k_finalize(const float* __restrict__ stats,
                                                  const float* __restrict__ colsum,
                                                  const float* __restrict__ gn_w,
                                                  const float* __restrict__ gn_b,
                                                  float* __restrict__ addend,
                                                  float* __restrict__ alphaArr) {
  int gid = blockIdx.x * 256 + threadIdx.x;   // 0..3071
  int bo = gid >> 6, d = gid & 63;
  int o = bo % 6;
  float s1 = stats[bo * 2], s2 = stats[bo * 2 + 1];
  const float inv = 1.f / 1048576.f;
  float mu = s1 * inv;
  float var = s2 * inv - mu * mu;
  float alpha = gn_w[o] * rsqrtf(var + 1e-5f * 1048576.f);
  float beta = gn_b[o] - alpha * mu;
  addend[gid] = beta * colsum[gid];
  if (d == 0) alphaArr[bo] = alpha;
}

// ---------------- apply: o_tmp = alpha*U + addend ----------------
__global__ __launch_bounds__(256) void k_apply(const float* __restrict__ Ug,
                                               const float* __restrict__ alphaArr,
                                               const float* __restrict__ addend,
                                               u16* __restrict__ otmp) {
  int i = blockIdx.x * 256 + threadIdx.x;
  int e = i * 4;
  int d4 = e & 63;
  int n = (e >> 6) & 1023;
  int bo = e >> 16;
  float al = alphaArr[bo];
  const float* ap = &addend[bo * 64 + d4];
  float4 u = *(const float4*)&Ug[e];
  int b = bo / 6, o = bo - b * 6;
  uint2 w;
  w.x = pk2(al * u.x + ap[0], al * u.y + ap[1]);
  w.y = pk2(al * u.z + ap[2], al * u.w + ap[3]);
  *(uint2*)&otmp[((size_t)(b * 1024 + n)) * 384 + o * 64 + d4] = w;
}

// ---------------- K6: out(F32) = o_tmp @ w_proj^T + b_proj ----------------
__global__ __launch_bounds__(256) void k_proj(const u16* __restrict__ A,
                                              const float* __restrict__ w,
                                              const float* __restrict__ bias,
                                              float* __restrict__ out) {
  __shared__ u16 As[128 * 64];
  __shared__ u16 Bs[128 * 64];
  const int t = threadIdx.x;
  const int m0 = blockIdx.x * 128;
  const int n0 = blockIdx.y * 128;
  const int wave = t >> 6, lane = t & 63;
  const int wm = (wave & 1) * 64, wn = (wave >> 1) * 64;
  const int fr = lane & 15;
  const int fk = (lane >> 4) * 8;
  f32x4 acc[4][4] = {};
  for (int k0 = 0; k0 < 384; k0 += 64) {
#pragma unroll
    for (int i = 0; i < 4; ++i) {
      int e = (i * 256 + t) * 8;
      int row = e >> 6, col = e & 63;
      *(uint4*)&As[e] = *(const uint4*)&A[(size_t)(m0 + row) * 384 + k0 + col];
      const float* wp = &w[(size_t)(n0 + row) * 384 + k0 + col];
      float4 b0 = *(const float4*)wp, b1 = *(const float4*)(wp + 4);
      uint4 bv; bv.x = pk2(b0.x, b0.y); bv.y = pk2(b0.z, b0.w);
      bv.z = pk2(b1.x, b1.y); bv.w = pk2(b1.z, b1.w);
      *(uint4*)&Bs[e] = bv;
    }
    __syncthreads();
#pragma unroll
    for (int ks = 0; ks < 2; ++ks) {
      const int ko = ks * 32 + fk;
      short8 a[4], b[4];
#pragma unroll
      for (int mi = 0; mi < 4; ++mi) a[mi] = *(const short8*)&As[(wm + mi * 16 + fr) * 64 + ko];
#pragma unroll
      for (int ni = 0; ni < 4; ++ni) b[ni] = *(const short8*)&Bs[(wn + ni * 16 + fr) * 64 + ko];
#pragma unroll
      for (int mi = 0; mi < 4; ++mi)
#pragma unroll
        for (int ni = 0; ni < 4; ++ni) acc[mi][ni] = MFMA(a[mi], b[ni], acc[mi][ni]);
    }
    __syncthreads();
  }
#pragma unroll
  for (int mi = 0; mi < 4; ++mi)
#pragma unroll
    for (int ni = 0; ni < 4; ++ni) {
      int gc = n0 + wn + ni * 16 + fr;
      float bv = bias[gc];
#pragma unroll
      for (int r = 0; r < 4; ++r) {
        int gm = m0 + wm + mi * 16 + (lane >> 4) * 4 + r;
        out[(size_t)gm * 384 + gc] = acc[mi][ni][r] + bv;   // FLOAT32 output
      }
    }
}

extern "C" void kernel_launch(void* const* d_in, const int* in_sizes, int n_in,
                              void* d_out, int out_size, void* d_ws, size_t ws_size,
                              hipStream_t stream) {
  (void)in_sizes; (void)n_in; (void)out_size; (void)ws_size;
  const float* x      = (const float*)d_in[0];
  const float* w_qkv  = (const float*)d_in[1];
  const float* w_proj = (const float*)d_in[2];
  const float* b_proj = (const float*)d_in[3];
  const float* w_kq   = (const float*)d_in[4];
  // d_in[5] b_kq: constant per map -> softmax-invariant, unused
  const float* w_head = (const float*)d_in[6];
  // d_in[7] b_head: constant per (b,o) map -> cancelled by GroupNorm, unused
  const float* gn_w   = (const float*)d_in[8];
  const float* gn_b   = (const float*)d_in[9];

  char* ws = (char*)d_ws;
  u16*   qb      = (u16*)(ws + OFF_Q);
  u16*   kb      = (u16*)(ws + OFF_K);
  u16*   vT      = (u16*)(ws + OFF_VT);
  u16*   Sb      = (u16*)(ws + OFF_S);
  float* Ug      = (float*)(ws + OFF_UG);   // aliases S (dead after conv)
  u16*   Qm      = (u16*)(ws + OFF_QM);
  u16*   otmp    = (u16*)(ws + OFF_OT);
  float* stats   = (float*)(ws + OFF_ST);
  float* colsum  = (float*)(ws + OFF_CS);
  float* addend  = (float*)(ws + OFF_AD);
  float* alphaA  = (float*)(ws + OFF_AL);

  hipMemsetAsync(stats, 0, 512, stream);
  k_qkv<<<dim3(64, 9), 256, 0, stream>>>(x, w_qkv, qb, kb, vT);
  k_qk<<<dim3(8, 8, 48), 256, 0, stream>>>(qb, kb, Sb);
  k_conv_softmax<<<dim3(128, 48), 256, 0, stream>>>(Sb, w_kq, Qm);
  k_colsum<<<dim3(48), 256, 0, stream>>>(vT, colsum);
  k_pvmix<<<dim3(16, 48), 256, 0, stream>>>(Qm, vT, w_head, Ug, stats);
  k_finalize<<<dim3(12), 256, 0, stream>>>(stats, colsum, gn_w, gn_b, addend, alphaA);
  k_apply<<<dim3(3072), 256, 0, stream>>>(Ug, alphaA, addend, otmp);
  k_proj<<<dim3(64, 3), 256, 0, stream>>>(otmp, w_proj, b_proj, (float*)d_out);
}